// Round 1
// baseline (1695.692 us; speedup 1.0000x reference)
//
#include <hip/hip_runtime.h>
#include <hip/hip_bf16.h>

#define NTOK 32768     // 2*128*128 pixel tokens
#define NPOOL 12800    // 2*80*80 pooled tokens

__device__ __forceinline__ float bf2f(unsigned short u) {
  return __uint_as_float(((unsigned int)u) << 16);
}
__device__ __forceinline__ unsigned short f2bf(float f) {
  __hip_bfloat16 h = __float2bfloat16(f);
  union { __hip_bfloat16 h; unsigned short u; } cv; cv.h = h; return cv.u;
}

// ---------------- Kernel 1: pooled map P[b,80,80,384] of reflect-padded x, 2x2 mean ----------------
__global__ __launch_bounds__(128) void pool_kernel(const float* __restrict__ x,
                                                   unsigned short* __restrict__ P) {
  int blk = blockIdx.x;                 // 0..12799  = b*6400 + p0*80 + p1
  int b = blk / 6400;
  int rem = blk - b * 6400;
  int p0 = rem / 80, p1 = rem - p0 * 80;
  int i0 = 2 * p0 - 16, i1 = i0 + 1;    // padded-row -> original index (reflect)
  int j0 = 2 * p1 - 16, j1 = j0 + 1;
  int r0 = i0 < 0 ? -i0 : (i0 > 127 ? 254 - i0 : i0);
  int r1 = i1 < 0 ? -i1 : (i1 > 127 ? 254 - i1 : i1);
  int c0 = j0 < 0 ? -j0 : (j0 > 127 ? 254 - j0 : j0);
  int c1 = j1 < 0 ? -j1 : (j1 > 127 ? 254 - j1 : j1);
  const float* s00 = x + (((size_t)b * 128 + r0) * 128 + c0) * 384;
  const float* s01 = x + (((size_t)b * 128 + r0) * 128 + c1) * 384;
  const float* s10 = x + (((size_t)b * 128 + r1) * 128 + c0) * 384;
  const float* s11 = x + (((size_t)b * 128 + r1) * 128 + c1) * 384;
  unsigned short* dst = P + (size_t)blk * 384;
  for (int c = threadIdx.x; c < 384; c += 128)
    dst[c] = f2bf(0.25f * (s00[c] + s01[c] + s10[c] + s11[c]));
}

// ---------------- Kernel 2: Y[M,384] = X[M,384] @ W[384,384] + bias ----------------
// 64x64 tile per 256-thread block, K-chunks of 16, fp32 accumulate.
template<int IN_BF16, int OUT_BF16>
__global__ __launch_bounds__(256) void proj_gemm(const void* __restrict__ Xv,
                                                 const float* __restrict__ W,
                                                 const float* __restrict__ bias,
                                                 void* __restrict__ Yv) {
  __shared__ float As[16][68];   // As[k][m], padded to avoid conflicts, 16B-aligned rows
  __shared__ float Bs[16][68];   // Bs[k][n]
  const int t = threadIdx.x;
  const int tx = t & 15, ty = t >> 4;
  const int m0 = blockIdx.x * 64, n0 = blockIdx.y * 64;
  float acc[4][4] = {};
  for (int k0 = 0; k0 < 384; k0 += 16) {
    if (IN_BF16) {
      if (t < 128) {
        const int m = t >> 1, k8 = (t & 1) << 3;
        const unsigned short* src = (const unsigned short*)Xv + ((size_t)(m0 + m)) * 384 + k0 + k8;
        uint4 u = *(const uint4*)src;
        const unsigned short* us = (const unsigned short*)&u;
        #pragma unroll
        for (int jj = 0; jj < 8; ++jj) As[k8 + jj][m] = bf2f(us[jj]);
      }
    } else {
      const int m = t >> 2, k4 = (t & 3) << 2;
      float4 v = *(const float4*)((const float*)Xv + ((size_t)(m0 + m)) * 384 + k0 + k4);
      As[k4 + 0][m] = v.x; As[k4 + 1][m] = v.y; As[k4 + 2][m] = v.z; As[k4 + 3][m] = v.w;
    }
    {
      const int k = t >> 4, n4 = (t & 15) << 2;
      float4 v = *(const float4*)(W + ((size_t)(k0 + k)) * 384 + n0 + n4);
      *(float4*)&Bs[k][n4] = v;
    }
    __syncthreads();
    #pragma unroll
    for (int k = 0; k < 16; ++k) {
      float4 a = *(const float4*)&As[k][ty << 2];
      float4 b = *(const float4*)&Bs[k][tx << 2];
      float av[4] = {a.x, a.y, a.z, a.w}, bv[4] = {b.x, b.y, b.z, b.w};
      #pragma unroll
      for (int i = 0; i < 4; ++i)
        #pragma unroll
        for (int j = 0; j < 4; ++j)
          acc[i][j] = fmaf(av[i], bv[j], acc[i][j]);
    }
    __syncthreads();
  }
  #pragma unroll
  for (int i = 0; i < 4; ++i) {
    const size_t row = m0 + (ty << 2) + i;
    if (OUT_BF16) {
      unsigned short u[4];
      #pragma unroll
      for (int j = 0; j < 4; ++j) u[j] = f2bf(acc[i][j] + bias[n0 + (tx << 2) + j]);
      *(ushort4*)((unsigned short*)Yv + row * 384 + n0 + (tx << 2)) =
          make_ushort4(u[0], u[1], u[2], u[3]);
    } else {
      float4 v = make_float4(acc[i][0] + bias[n0 + (tx << 2) + 0],
                             acc[i][1] + bias[n0 + (tx << 2) + 1],
                             acc[i][2] + bias[n0 + (tx << 2) + 2],
                             acc[i][3] + bias[n0 + (tx << 2) + 3]);
      *(float4*)((float*)Yv + row * 384 + n0 + (tx << 2)) = v;
    }
  }
}

// ---------------- Kernel 3: attention, one block per (window, head), one thread per q row ----------------
// kv layout: tiles of 64; tiles 0-3 = offsets 0..3 (pooled), 4-7 = center 256, 8-11 = offsets 5..8.
__global__ __launch_bounds__(256) void attn_kernel(const unsigned short* __restrict__ Q,
                                                   const unsigned short* __restrict__ Kc,
                                                   const unsigned short* __restrict__ Vc,
                                                   const float* __restrict__ pb,
                                                   unsigned short* __restrict__ AttOut) {
  __shared__ int kvbase[768];     // element offset (incl. head*48) into Kc/Vc
  __shared__ float tilebias[12];
  __shared__ float Ks[64][48];
  __shared__ float Vs[64][48];
  const int t = threadIdx.x;
  const int head = blockIdx.x & 7, win = blockIdx.x >> 3;
  const int b = win >> 6, wrem = win & 63, wi = wrem >> 3, wj = wrem & 7;

  for (int j = t; j < 768; j += 256) {
    int o, within;
    if (j < 256)      { o = j >> 6;              within = j & 63; }
    else if (j < 512) { o = 4;                   within = j - 256; }
    else              { o = 5 + ((j - 512) >> 6); within = j & 63; }
    int base;
    if (o == 4) {
      int r = within >> 4, c = within & 15;
      base = ((b * 128 + wi * 16 + r) * 128 + wj * 16 + c) * 384;
    } else {
      int di = o / 3 - 1, dj = o - (o / 3) * 3 - 1;
      int t0 = within >> 3, t1 = within & 7;
      int p0 = 8 * (1 + di + wi) + t0, p1 = 8 * (1 + dj + wj) + t1;
      base = (NTOK + (b * 80 + p0) * 80 + p1) * 384;
    }
    kvbase[j] = base + head * 48;
  }
  if (t < 12) {
    int o = t < 4 ? t : (t < 8 ? 4 : t - 3);
    tilebias[t] = (o == 4) ? 0.0f : -pb[head * 9 + o];
  }

  const int r = t >> 4, c = t & 15;
  const size_t qtok = ((size_t)b * 128 + wi * 16 + r) * 128 + wj * 16 + c;
  float qreg[48];
  {
    const unsigned short* qp = Q + qtok * 384 + head * 48;
    #pragma unroll
    for (int dd = 0; dd < 48; dd += 8) {
      uint4 u = *(const uint4*)(qp + dd);
      const unsigned short* us = (const unsigned short*)&u;
      #pragma unroll
      for (int jj = 0; jj < 8; ++jj) qreg[dd + jj] = bf2f(us[jj]);
    }
  }
  float mrun = -3.0e38f, lrun = 0.0f;
  float Oacc[48];
  #pragma unroll
  for (int d = 0; d < 48; ++d) Oacc[d] = 0.0f;
  const float scale = 0.14433756729740643f;  // 48^-0.5

  for (int T = 0; T < 12; ++T) {
    __syncthreads();   // also covers kvbase/tilebias on first iter
    for (int u = t; u < 384; u += 256) {     // 64 tokens x 6 chunks of 8 elems
      const int tok = u / 6, ch = u - tok * 6;
      const int gbase = kvbase[T * 64 + tok] + ch * 8;
      uint4 ku = *(const uint4*)(Kc + gbase);
      uint4 vu = *(const uint4*)(Vc + gbase);
      const unsigned short* kus = (const unsigned short*)&ku;
      const unsigned short* vus = (const unsigned short*)&vu;
      #pragma unroll
      for (int jj = 0; jj < 8; ++jj) {
        Ks[tok][ch * 8 + jj] = bf2f(kus[jj]);
        Vs[tok][ch * 8 + jj] = bf2f(vus[jj]);
      }
    }
    __syncthreads();
    const float tb = tilebias[T];
    for (int j0 = 0; j0 < 64; j0 += 16) {
      float s[16];
      #pragma unroll
      for (int jj = 0; jj < 16; ++jj) {
        const float* kr = Ks[j0 + jj];
        float a0 = 0, a1 = 0, a2 = 0, a3 = 0;
        #pragma unroll
        for (int dd = 0; dd < 48; dd += 4) {
          float4 k4 = *(const float4*)(kr + dd);   // uniform addr -> LDS broadcast
          a0 = fmaf(qreg[dd + 0], k4.x, a0);
          a1 = fmaf(qreg[dd + 1], k4.y, a1);
          a2 = fmaf(qreg[dd + 2], k4.z, a2);
          a3 = fmaf(qreg[dd + 3], k4.w, a3);
        }
        s[jj] = (a0 + a1 + a2 + a3) * scale + tb;
      }
      float tmax = s[0];
      #pragma unroll
      for (int jj = 1; jj < 16; ++jj) tmax = fmaxf(tmax, s[jj]);
      const float mnew = fmaxf(mrun, tmax);
      const float corr = __expf(mrun - mnew);
      lrun *= corr;
      #pragma unroll
      for (int d = 0; d < 48; ++d) Oacc[d] *= corr;
      mrun = mnew;
      #pragma unroll
      for (int jj = 0; jj < 16; ++jj) {
        const float p = __expf(s[jj] - mrun);
        lrun += p;
        const float* vr = Vs[j0 + jj];
        #pragma unroll
        for (int dd = 0; dd < 48; dd += 4) {
          float4 v4 = *(const float4*)(vr + dd);
          Oacc[dd + 0] = fmaf(p, v4.x, Oacc[dd + 0]);
          Oacc[dd + 1] = fmaf(p, v4.y, Oacc[dd + 1]);
          Oacc[dd + 2] = fmaf(p, v4.z, Oacc[dd + 2]);
          Oacc[dd + 3] = fmaf(p, v4.w, Oacc[dd + 3]);
        }
      }
    }
  }
  const float inv = 1.0f / lrun;
  unsigned short* op = AttOut + qtok * 384 + head * 48;
  #pragma unroll
  for (int dd = 0; dd < 48; dd += 4) {
    ushort4 u4 = make_ushort4(f2bf(Oacc[dd] * inv), f2bf(Oacc[dd + 1] * inv),
                              f2bf(Oacc[dd + 2] * inv), f2bf(Oacc[dd + 3] * inv));
    *(ushort4*)(op + dd) = u4;
  }
}

extern "C" void kernel_launch(void* const* d_in, const int* in_sizes, int n_in,
                              void* d_out, int out_size, void* d_ws, size_t ws_size,
                              hipStream_t stream) {
  const float* x  = (const float*)d_in[0];
  const float* Wq = (const float*)d_in[1];
  const float* bq = (const float*)d_in[2];
  const float* Wk = (const float*)d_in[3];
  const float* bk = (const float*)d_in[4];
  const float* Wv = (const float*)d_in[5];
  const float* bv = (const float*)d_in[6];
  const float* Wo = (const float*)d_in[7];
  const float* bo = (const float*)d_in[8];
  const float* pb = (const float*)d_in[9];

  // ws layout (bytes), all bf16 intermediates, total ~130.2 MB:
  //   P    : 12800*384*2 = 9,830,400
  //   Q    : 32768*384*2 = 25,165,824
  //   Kcat : 45568*384*2 = 34,996,224   (Kx tokens 0..32767, then Kp)
  //   Vcat : 45568*384*2 = 34,996,224
  //   AttO : 32768*384*2 = 25,165,824
  char* ws = (char*)d_ws;
  unsigned short* P    = (unsigned short*)(ws);
  unsigned short* Qb   = (unsigned short*)(ws + 9830400ull);
  unsigned short* Kcat = (unsigned short*)(ws + 9830400ull + 25165824ull);
  unsigned short* Vcat = (unsigned short*)(ws + 9830400ull + 25165824ull + 34996224ull);
  unsigned short* AttO = (unsigned short*)(ws + 9830400ull + 25165824ull + 2ull * 34996224ull);

  pool_kernel<<<12800, 128, 0, stream>>>(x, P);
  dim3 g1(512, 6), g2(200, 6);
  proj_gemm<0, 1><<<g1, 256, 0, stream>>>(x, Wq, bq, Qb);
  proj_gemm<0, 1><<<g1, 256, 0, stream>>>(x, Wk, bk, Kcat);
  proj_gemm<0, 1><<<g1, 256, 0, stream>>>(x, Wv, bv, Vcat);
  proj_gemm<1, 1><<<g2, 256, 0, stream>>>(P, Wk, bk, Kcat + (size_t)NTOK * 384);
  proj_gemm<1, 1><<<g2, 256, 0, stream>>>(P, Wv, bv, Vcat + (size_t)NTOK * 384);
  attn_kernel<<<128 * 8, 256, 0, stream>>>(Qb, Kcat, Vcat, pb, AttO);
  proj_gemm<1, 0><<<g1, 256, 0, stream>>>(AttO, Wo, bo, (float*)d_out);
}

// Round 2
// 272.508 us; speedup vs baseline: 6.2225x; 6.2225x over previous
//
#include <hip/hip_runtime.h>
#include <hip/hip_bf16.h>

#define NTOK 32768     // 2*128*128 pixel tokens
#define NPOOL 12800    // 2*80*80 pooled tokens

typedef __attribute__((ext_vector_type(8))) short bf16x8;
typedef __attribute__((ext_vector_type(4))) float f32x4;

__device__ __forceinline__ float bf2f(unsigned short u) {
  return __uint_as_float(((unsigned int)u) << 16);
}
__device__ __forceinline__ unsigned short f2bf(float f) {
  union { __hip_bfloat16 h; unsigned short u; } cv;
  cv.h = __float2bfloat16(f);
  return cv.u;
}

__device__ __forceinline__ void gload16(const void* g, void* l) {
  __builtin_amdgcn_global_load_lds(
      (const __attribute__((address_space(1))) unsigned int*)(unsigned long long)g,
      (__attribute__((address_space(3))) unsigned int*)(unsigned long long)l, 16, 0, 0);
}

// ---------------- x f32 -> bf16 ----------------
__global__ __launch_bounds__(256) void convert_x(const float* __restrict__ x,
                                                 unsigned short* __restrict__ xb) {
  const int i = (blockIdx.x * 256 + threadIdx.x) * 8;
  float4 a = *(const float4*)(x + i);
  float4 b = *(const float4*)(x + i + 4);
  *(ushort4*)(xb + i)     = make_ushort4(f2bf(a.x), f2bf(a.y), f2bf(a.z), f2bf(a.w));
  *(ushort4*)(xb + i + 4) = make_ushort4(f2bf(b.x), f2bf(b.y), f2bf(b.z), f2bf(b.w));
}

// ---------------- W[k][n] f32 -> Wt[n][k] bf16, 4 matrices ----------------
__global__ __launch_bounds__(256) void transpose_w(const float* __restrict__ Wq,
                                                   const float* __restrict__ Wk,
                                                   const float* __restrict__ Wv,
                                                   const float* __restrict__ Wo,
                                                   unsigned short* __restrict__ Wt) {
  __shared__ float tile[32][33];
  const int wsel = blockIdx.z;
  const float* W = (wsel == 0) ? Wq : (wsel == 1) ? Wk : (wsel == 2) ? Wv : Wo;
  unsigned short* out = Wt + (size_t)wsel * 147456;
  const int k0 = blockIdx.x * 32, n0 = blockIdx.y * 32;
  const int r = threadIdx.x >> 3, c4 = (threadIdx.x & 7) * 4;
  float4 v = *(const float4*)&W[(size_t)(k0 + r) * 384 + n0 + c4];
  tile[r][c4 + 0] = v.x; tile[r][c4 + 1] = v.y; tile[r][c4 + 2] = v.z; tile[r][c4 + 3] = v.w;
  __syncthreads();
  ushort4 o = make_ushort4(f2bf(tile[c4 + 0][r]), f2bf(tile[c4 + 1][r]),
                           f2bf(tile[c4 + 2][r]), f2bf(tile[c4 + 3][r]));
  *(ushort4*)&out[(size_t)(n0 + r) * 384 + k0 + c4] = o;
}

// ---------------- pooled map P[b,80,80,384] of reflect-padded x, 2x2 mean ----------------
__global__ __launch_bounds__(128) void pool_kernel(const float* __restrict__ x,
                                                   unsigned short* __restrict__ P) {
  int blk = blockIdx.x;
  int b = blk / 6400;
  int rem = blk - b * 6400;
  int p0 = rem / 80, p1 = rem - p0 * 80;
  int i0 = 2 * p0 - 16, i1 = i0 + 1;
  int j0 = 2 * p1 - 16, j1 = j0 + 1;
  int r0 = i0 < 0 ? -i0 : (i0 > 127 ? 254 - i0 : i0);
  int r1 = i1 < 0 ? -i1 : (i1 > 127 ? 254 - i1 : i1);
  int c0 = j0 < 0 ? -j0 : (j0 > 127 ? 254 - j0 : j0);
  int c1 = j1 < 0 ? -j1 : (j1 > 127 ? 254 - j1 : j1);
  const float* s00 = x + (((size_t)b * 128 + r0) * 128 + c0) * 384;
  const float* s01 = x + (((size_t)b * 128 + r0) * 128 + c1) * 384;
  const float* s10 = x + (((size_t)b * 128 + r1) * 128 + c0) * 384;
  const float* s11 = x + (((size_t)b * 128 + r1) * 128 + c1) * 384;
  unsigned short* dst = P + (size_t)blk * 384;
  for (int c = threadIdx.x; c < 384; c += 128)
    dst[c] = f2bf(0.25f * (s00[c] + s01[c] + s10[c] + s11[c]));
}

// ---------------- MFMA GEMM: Y[M,384] = X[M,384](bf16) @ Wt^T + bias ----------------
// Wt is [384 n][384 k] bf16 (pre-transposed). 128x128 tile, BK=32, 4 waves.
template<int OUT_F32>
__global__ __launch_bounds__(256) void mfma_proj(const unsigned short* __restrict__ X,
                                                 const unsigned short* __restrict__ Wt,
                                                 const float* __restrict__ bias,
                                                 void* __restrict__ Y) {
  __shared__ __attribute__((aligned(16))) unsigned short As[128 * 32];
  __shared__ __attribute__((aligned(16))) unsigned short Bs[128 * 32];
  const int t = threadIdx.x;
  const int w = t >> 6, l = t & 63, l15 = l & 15, g = l >> 4;
  const int wm = w >> 1, wn = w & 1;
  const int m0 = blockIdx.x * 128, n0 = blockIdx.y * 128;

  f32x4 acc[4][4];
  #pragma unroll
  for (int i = 0; i < 4; ++i)
    #pragma unroll
    for (int j = 0; j < 4; ++j) acc[i][j] = {0.f, 0.f, 0.f, 0.f};

  for (int k0 = 0; k0 < 384; k0 += 32) {
    __syncthreads();
    #pragma unroll
    for (int a = 0; a < 2; ++a) {
      const int c = w * 2 + a;
      const int row = c * 16 + (l >> 2), kc = (l & 3) * 8;
      gload16(X  + (size_t)(m0 + row) * 384 + k0 + kc, As + c * 512);
      gload16(Wt + (size_t)(n0 + row) * 384 + k0 + kc, Bs + c * 512);
    }
    __syncthreads();
    bf16x8 af[4], bfr[4];
    #pragma unroll
    for (int mi = 0; mi < 4; ++mi)
      af[mi] = *(const bf16x8*)(As + (wm * 64 + mi * 16 + l15) * 32 + g * 8);
    #pragma unroll
    for (int nj = 0; nj < 4; ++nj)
      bfr[nj] = *(const bf16x8*)(Bs + (wn * 64 + nj * 16 + l15) * 32 + g * 8);
    #pragma unroll
    for (int mi = 0; mi < 4; ++mi)
      #pragma unroll
      for (int nj = 0; nj < 4; ++nj)
        acc[mi][nj] = __builtin_amdgcn_mfma_f32_16x16x32_bf16(af[mi], bfr[nj], acc[mi][nj], 0, 0, 0);
  }

  float bv[4];
  #pragma unroll
  for (int nj = 0; nj < 4; ++nj) bv[nj] = bias[n0 + wn * 64 + nj * 16 + l15];
  #pragma unroll
  for (int mi = 0; mi < 4; ++mi)
    #pragma unroll
    for (int nj = 0; nj < 4; ++nj)
      #pragma unroll
      for (int r = 0; r < 4; ++r) {
        const size_t row = m0 + wm * 64 + mi * 16 + g * 4 + r;
        const size_t col = n0 + wn * 64 + nj * 16 + l15;
        float v = acc[mi][nj][r] + bv[nj];
        if (OUT_F32) ((float*)Y)[row * 384 + col] = v;
        else         ((unsigned short*)Y)[row * 384 + col] = f2bf(v);
      }
}

// ---------------- MFMA flash attention ----------------
// One block per (head, window). 4 waves x 64 q-rows. KV tiles of 32 (24 tiles).
// Swapped QK^T: S^T = K*Q^T so softmax row-reduce is mostly in-lane.
__global__ __launch_bounds__(256) void attn_mfma(const unsigned short* __restrict__ Qg,
                                                 const unsigned short* __restrict__ Kc,
                                                 const unsigned short* __restrict__ Vc,
                                                 const float* __restrict__ pb,
                                                 unsigned short* __restrict__ AttO) {
  __shared__ int kvbase[768];
  __shared__ float tb2s[24];
  __shared__ __attribute__((aligned(16))) unsigned short Ks[32 * 56];   // [kv][d] pad 56
  __shared__ __attribute__((aligned(16))) unsigned short Vt[48 * 52];   // [d][kv] pad 52
  __shared__ __attribute__((aligned(16))) unsigned short Ps[4][64 * 36];// per-wave [q][kv swz]

  const int t = threadIdx.x;
  const int head = blockIdx.x >> 7, win = blockIdx.x & 127;
  const int b = win >> 6, wrem = win & 63, wi = wrem >> 3, wj = wrem & 7;
  const int w = t >> 6, l = t & 63, l15 = l & 15, g = l >> 4;

  for (int j = t; j < 768; j += 256) {
    int o, within;
    if (j < 256)      { o = j >> 6;               within = j & 63; }
    else if (j < 512) { o = 4;                    within = j - 256; }
    else              { o = 5 + ((j - 512) >> 6); within = j & 63; }
    int base;
    if (o == 4) {
      int r = within >> 4, c = within & 15;
      base = ((b * 128 + wi * 16 + r) * 128 + wj * 16 + c) * 384;
    } else {
      int di = o / 3 - 1, dj = o - (o / 3) * 3 - 1;
      int t0 = within >> 3, t1 = within & 7;
      int p0 = 8 * (1 + di + wi) + t0, p1 = 8 * (1 + dj + wj) + t1;
      base = (NTOK + (b * 80 + p0) * 80 + p1) * 384;
    }
    kvbase[j] = base + head * 48;
  }
  if (t < 24) {
    int o = (t < 8) ? (t >> 1) : ((t < 16) ? 4 : 5 + ((t - 16) >> 1));
    tb2s[t] = (o == 4) ? 0.0f : (-pb[head * 9 + o] * 1.4426950408889634f);
  }

  const float SCALE2 = 0.14433756729740643f * 1.4426950408889634f;  // 48^-0.5 * log2e
  const bf16x8 z8 = {0, 0, 0, 0, 0, 0, 0, 0};

  bf16x8 qf[4][2];
  #pragma unroll
  for (int nf = 0; nf < 4; ++nf) {
    const int tok = ((b * 128 + wi * 16 + w * 4 + nf) * 128 + wj * 16 + l15);
    const unsigned short* qp = Qg + (size_t)tok * 384 + head * 48;
    qf[nf][0] = *(const bf16x8*)(qp + g * 8);
    qf[nf][1] = (g < 2) ? *(const bf16x8*)(qp + 32 + g * 8) : z8;
  }

  float mrun[4], lrun[4];
  f32x4 Oacc[3][4];
  #pragma unroll
  for (int nf = 0; nf < 4; ++nf) { mrun[nf] = -1e30f; lrun[nf] = 0.f; }
  #pragma unroll
  for (int mo = 0; mo < 3; ++mo)
    #pragma unroll
    for (int nf = 0; nf < 4; ++nf) Oacc[mo][nf] = {0.f, 0.f, 0.f, 0.f};

  for (int T = 0; T < 24; ++T) {
    __syncthreads();
    if (t < 192) {
      const int tok = t & 31, ch = t >> 5;
      const int gb = kvbase[T * 32 + tok] + ch * 8;
      uint4 ku = *(const uint4*)(Kc + gb);
      *(uint4*)&Ks[tok * 56 + ch * 8] = ku;
      uint4 vu = *(const uint4*)(Vc + gb);
      const unsigned short* vus = (const unsigned short*)&vu;
      #pragma unroll
      for (int s = 0; s < 8; ++s) Vt[(ch * 8 + s) * 52 + tok] = vus[s];
    }
    __syncthreads();

    // S^T[kv32][q64] = K * Q^T
    f32x4 sf[2][4];
    #pragma unroll
    for (int mi = 0; mi < 2; ++mi)
      #pragma unroll
      for (int nf = 0; nf < 4; ++nf) sf[mi][nf] = {0.f, 0.f, 0.f, 0.f};
    #pragma unroll
    for (int mi = 0; mi < 2; ++mi) {
      bf16x8 ka0 = *(const bf16x8*)&Ks[(mi * 16 + l15) * 56 + g * 8];
      bf16x8 ka1 = (g < 2) ? *(const bf16x8*)&Ks[(mi * 16 + l15) * 56 + 32 + g * 8] : z8;
      #pragma unroll
      for (int nf = 0; nf < 4; ++nf) {
        sf[mi][nf] = __builtin_amdgcn_mfma_f32_16x16x32_bf16(ka0, qf[nf][0], sf[mi][nf], 0, 0, 0);
        sf[mi][nf] = __builtin_amdgcn_mfma_f32_16x16x32_bf16(ka1, qf[nf][1], sf[mi][nf], 0, 0, 0);
      }
    }

    const float tb = tb2s[T];
    #pragma unroll
    for (int nf = 0; nf < 4; ++nf) {
      float s0[8];
      #pragma unroll
      for (int mi = 0; mi < 2; ++mi)
        #pragma unroll
        for (int r = 0; r < 4; ++r) s0[mi * 4 + r] = fmaf(sf[mi][nf][r], SCALE2, tb);
      float tmax = s0[0];
      #pragma unroll
      for (int i = 1; i < 8; ++i) tmax = fmaxf(tmax, s0[i]);
      tmax = fmaxf(tmax, __shfl_xor(tmax, 16));
      tmax = fmaxf(tmax, __shfl_xor(tmax, 32));
      const float mnew = fmaxf(mrun[nf], tmax);
      const float corr = exp2f(mrun[nf] - mnew);
      float p[8], ps = 0.f;
      #pragma unroll
      for (int i = 0; i < 8; ++i) { p[i] = exp2f(s0[i] - mnew); ps += p[i]; }
      ps += __shfl_xor(ps, 16);
      ps += __shfl_xor(ps, 32);
      lrun[nf] = lrun[nf] * corr + ps;
      mrun[nf] = mnew;
      #pragma unroll
      for (int mo = 0; mo < 3; ++mo) {
        Oacc[mo][nf][0] *= corr; Oacc[mo][nf][1] *= corr;
        Oacc[mo][nf][2] *= corr; Oacc[mo][nf][3] *= corr;
      }
      #pragma unroll
      for (int mi = 0; mi < 2; ++mi) {
        ushort4 pk = make_ushort4(f2bf(p[mi * 4 + 0]), f2bf(p[mi * 4 + 1]),
                                  f2bf(p[mi * 4 + 2]), f2bf(p[mi * 4 + 3]));
        const int chunk = mi * 2 + (g >> 1);
        *(ushort4*)&Ps[w][(nf * 16 + l15) * 36 + ((chunk ^ (l15 & 3)) << 3) + ((g & 1) << 2)] = pk;
      }
    }

    // O^T += V^T * P^T
    bf16x8 pbf[4];
    #pragma unroll
    for (int nf = 0; nf < 4; ++nf) {
      const unsigned short* pp = &Ps[w][(nf * 16 + l15) * 36 + ((g ^ (l15 & 3)) << 3)];
      union { bf16x8 v; ushort4 u[2]; } cv;
      cv.u[0] = *(const ushort4*)pp;
      cv.u[1] = *(const ushort4*)(pp + 4);
      pbf[nf] = cv.v;
    }
    #pragma unroll
    for (int mo = 0; mo < 3; ++mo) {
      const unsigned short* vp = &Vt[(mo * 16 + l15) * 52 + g * 8];
      union { bf16x8 v; ushort4 u[2]; } cv;
      cv.u[0] = *(const ushort4*)vp;
      cv.u[1] = *(const ushort4*)(vp + 4);
      bf16x8 va = cv.v;
      #pragma unroll
      for (int nf = 0; nf < 4; ++nf)
        Oacc[mo][nf] = __builtin_amdgcn_mfma_f32_16x16x32_bf16(va, pbf[nf], Oacc[mo][nf], 0, 0, 0);
    }
  }

  #pragma unroll
  for (int nf = 0; nf < 4; ++nf) {
    const float inv = 1.0f / lrun[nf];
    const int tok = ((b * 128 + wi * 16 + w * 4 + nf) * 128 + wj * 16 + l15);
    unsigned short* op = AttO + (size_t)tok * 384 + head * 48;
    #pragma unroll
    for (int mo = 0; mo < 3; ++mo) {
      ushort4 u = make_ushort4(f2bf(Oacc[mo][nf][0] * inv), f2bf(Oacc[mo][nf][1] * inv),
                               f2bf(Oacc[mo][nf][2] * inv), f2bf(Oacc[mo][nf][3] * inv));
      *(ushort4*)(op + mo * 16 + g * 4) = u;
    }
  }
}

extern "C" void kernel_launch(void* const* d_in, const int* in_sizes, int n_in,
                              void* d_out, int out_size, void* d_ws, size_t ws_size,
                              hipStream_t stream) {
  const float* x  = (const float*)d_in[0];
  const float* Wq = (const float*)d_in[1];
  const float* bq = (const float*)d_in[2];
  const float* Wk = (const float*)d_in[3];
  const float* bk = (const float*)d_in[4];
  const float* Wv = (const float*)d_in[5];
  const float* bv = (const float*)d_in[6];
  const float* Wo = (const float*)d_in[7];
  const float* bo = (const float*)d_in[8];
  const float* pb = (const float*)d_in[9];

  // ws layout (bytes), total 106,168,320:
  //   Wt   : 4*384*384*2 = 1,179,648
  //   P    : 12800*384*2 = 9,830,400
  //   Kcat : 45568*384*2 = 34,996,224
  //   Vcat : 45568*384*2 = 34,996,224
  //   xb/AttO (aliased, sequential lifetimes): 32768*384*2 = 25,165,824
  // Qb lives in d_out's first half (dead before final proj writes d_out).
  char* ws = (char*)d_ws;
  unsigned short* Wt   = (unsigned short*)(ws);
  unsigned short* P    = (unsigned short*)(ws + 1179648ull);
  unsigned short* Kcat = (unsigned short*)(ws + 11010048ull);
  unsigned short* Vcat = (unsigned short*)(ws + 46006272ull);
  unsigned short* xb   = (unsigned short*)(ws + 81002496ull);
  unsigned short* AttO = xb;
  unsigned short* Qb   = (unsigned short*)d_out;

  convert_x<<<6144, 256, 0, stream>>>(x, xb);
  transpose_w<<<dim3(12, 12, 4), 256, 0, stream>>>(Wq, Wk, Wv, Wo, Wt);
  pool_kernel<<<12800, 128, 0, stream>>>(x, P);
  mfma_proj<0><<<dim3(256, 3), 256, 0, stream>>>(xb, Wt + 0 * 147456, bq, Qb);
  mfma_proj<0><<<dim3(256, 3), 256, 0, stream>>>(xb, Wt + 1 * 147456, bk, Kcat);
  mfma_proj<0><<<dim3(256, 3), 256, 0, stream>>>(xb, Wt + 2 * 147456, bv, Vcat);
  mfma_proj<0><<<dim3(100, 3), 256, 0, stream>>>(P, Wt + 1 * 147456, bk, Kcat + (size_t)NTOK * 384);
  mfma_proj<0><<<dim3(100, 3), 256, 0, stream>>>(P, Wt + 2 * 147456, bv, Vcat + (size_t)NTOK * 384);
  attn_mfma<<<1024, 256, 0, stream>>>(Qb, Kcat, Vcat, pb, AttO);
  mfma_proj<1><<<dim3(256, 3), 256, 0, stream>>>(AttO, Wt + 3 * 147456, bo, (float*)d_out);
}

// Round 3
// 202.207 us; speedup vs baseline: 8.3859x; 1.3477x over previous
//
#include <hip/hip_runtime.h>
#include <hip/hip_bf16.h>

#define NTOK 32768     // 2*128*128 pixel tokens
#define LOG2E 1.4426950408889634f

typedef __attribute__((ext_vector_type(8))) short bf16x8;
typedef __attribute__((ext_vector_type(4))) float f32x4;

__device__ __forceinline__ float bf2f(unsigned short u) {
  return __uint_as_float(((unsigned int)u) << 16);
}
__device__ __forceinline__ unsigned short f2bf(float f) {
  union { __hip_bfloat16 h; unsigned short u; } cv;
  cv.h = __float2bfloat16(f);
  return cv.u;
}
__device__ __forceinline__ float fast_exp2(float x) {
#if __has_builtin(__builtin_amdgcn_exp2f)
  return __builtin_amdgcn_exp2f(x);
#else
  return exp2f(x);
#endif
}

__device__ __forceinline__ void gload16(const void* g, void* l) {
  __builtin_amdgcn_global_load_lds(
      (const __attribute__((address_space(1))) unsigned int*)(unsigned long long)g,
      (__attribute__((address_space(3))) unsigned int*)(unsigned long long)l, 16, 0, 0);
}

// ---------------- x f32 -> bf16 ----------------
__global__ __launch_bounds__(256) void convert_x(const float* __restrict__ x,
                                                 unsigned short* __restrict__ xb) {
  const int i = (blockIdx.x * 256 + threadIdx.x) * 8;
  float4 a = *(const float4*)(x + i);
  float4 b = *(const float4*)(x + i + 4);
  *(ushort4*)(xb + i)     = make_ushort4(f2bf(a.x), f2bf(a.y), f2bf(a.z), f2bf(a.w));
  *(ushort4*)(xb + i + 4) = make_ushort4(f2bf(b.x), f2bf(b.y), f2bf(b.z), f2bf(b.w));
}

// ---------------- W[k][n] f32 -> Wt[n][k] bf16, 4 matrices ----------------
__global__ __launch_bounds__(256) void transpose_w(const float* __restrict__ Wq,
                                                   const float* __restrict__ Wk,
                                                   const float* __restrict__ Wv,
                                                   const float* __restrict__ Wo,
                                                   unsigned short* __restrict__ Wt) {
  __shared__ float tile[32][33];
  const int wsel = blockIdx.z;
  const float* W = (wsel == 0) ? Wq : (wsel == 1) ? Wk : (wsel == 2) ? Wv : Wo;
  unsigned short* out = Wt + (size_t)wsel * 147456;
  const int k0 = blockIdx.x * 32, n0 = blockIdx.y * 32;
  const int r = threadIdx.x >> 3, c4 = (threadIdx.x & 7) * 4;
  float4 v = *(const float4*)&W[(size_t)(k0 + r) * 384 + n0 + c4];
  tile[r][c4 + 0] = v.x; tile[r][c4 + 1] = v.y; tile[r][c4 + 2] = v.z; tile[r][c4 + 3] = v.w;
  __syncthreads();
  ushort4 o = make_ushort4(f2bf(tile[c4 + 0][r]), f2bf(tile[c4 + 1][r]),
                           f2bf(tile[c4 + 2][r]), f2bf(tile[c4 + 3][r]));
  *(ushort4*)&out[(size_t)(n0 + r) * 384 + k0 + c4] = o;
}

// ---------------- pooled map P (bf16 in, bf16 out) ----------------
__global__ __launch_bounds__(128) void pool_kernel(const unsigned short* __restrict__ xb,
                                                   unsigned short* __restrict__ P) {
  int blk = blockIdx.x;
  int b = blk / 6400;
  int rem = blk - b * 6400;
  int p0 = rem / 80, p1 = rem - p0 * 80;
  int i0 = 2 * p0 - 16, i1 = i0 + 1;
  int j0 = 2 * p1 - 16, j1 = j0 + 1;
  int r0 = i0 < 0 ? -i0 : (i0 > 127 ? 254 - i0 : i0);
  int r1 = i1 < 0 ? -i1 : (i1 > 127 ? 254 - i1 : i1);
  int c0 = j0 < 0 ? -j0 : (j0 > 127 ? 254 - j0 : j0);
  int c1 = j1 < 0 ? -j1 : (j1 > 127 ? 254 - j1 : j1);
  const unsigned short* s00 = xb + (((size_t)b * 128 + r0) * 128 + c0) * 384;
  const unsigned short* s01 = xb + (((size_t)b * 128 + r0) * 128 + c1) * 384;
  const unsigned short* s10 = xb + (((size_t)b * 128 + r1) * 128 + c0) * 384;
  const unsigned short* s11 = xb + (((size_t)b * 128 + r1) * 128 + c1) * 384;
  unsigned short* dst = P + (size_t)blk * 384;
  for (int c = threadIdx.x; c < 384; c += 128)
    dst[c] = f2bf(0.25f * (bf2f(s00[c]) + bf2f(s01[c]) + bf2f(s10[c]) + bf2f(s11[c])));
}

// ---------------- fused QKV (+pooled KV) projection ----------------
// blockIdx.x: 0-8 main (q,k,v x 3 col-blocks), 9-14 pooled (k,v x 3 col-blocks).
// blockIdx.y: row tile. n-fastest dispatch -> A-tile shared across consecutive blocks.
__global__ __launch_bounds__(256) void mfma_proj_fused(
    const unsigned short* __restrict__ xb, const unsigned short* __restrict__ P,
    const unsigned short* __restrict__ Wt,
    const float* __restrict__ bq, const float* __restrict__ bk, const float* __restrict__ bv,
    unsigned short* __restrict__ Qb, unsigned short* __restrict__ Kcat,
    unsigned short* __restrict__ Vcat) {
  const int xx = blockIdx.x, yy = blockIdx.y;
  const unsigned short* X;
  int wsel; size_t off;
  if (xx < 9) { X = xb; wsel = xx / 3; off = 0; }
  else { if (yy >= 100) return; X = P; wsel = 1 + (xx - 9) / 3; off = (size_t)NTOK * 384; }
  const float* bias = (wsel == 0) ? bq : (wsel == 1) ? bk : bv;
  unsigned short* Y = ((wsel == 0) ? Qb : (wsel == 1) ? Kcat : Vcat) + off;
  const unsigned short* Wm = Wt + (size_t)wsel * 147456;
  const int n0 = ((xx < 9) ? (xx % 3) : ((xx - 9) % 3)) * 128;
  const int m0 = yy * 128;

  __shared__ __attribute__((aligned(16))) unsigned short As[128 * 32];
  __shared__ __attribute__((aligned(16))) unsigned short Bs[128 * 32];
  const int t = threadIdx.x;
  const int w = t >> 6, l = t & 63, l15 = l & 15, g = l >> 4;
  const int wm = w >> 1, wn = w & 1;

  f32x4 acc[4][4];
  #pragma unroll
  for (int i = 0; i < 4; ++i)
    #pragma unroll
    for (int j = 0; j < 4; ++j) acc[i][j] = {0.f, 0.f, 0.f, 0.f};

  for (int k0 = 0; k0 < 384; k0 += 32) {
    __syncthreads();
    #pragma unroll
    for (int a = 0; a < 2; ++a) {
      const int c = w * 2 + a;
      const int row = c * 16 + (l >> 2), kc = (l & 3) * 8;
      gload16(X  + (size_t)(m0 + row) * 384 + k0 + kc, As + c * 512);
      gload16(Wm + (size_t)(n0 + row) * 384 + k0 + kc, Bs + c * 512);
    }
    __syncthreads();
    bf16x8 af[4], bfr[4];
    #pragma unroll
    for (int mi = 0; mi < 4; ++mi)
      af[mi] = *(const bf16x8*)(As + (wm * 64 + mi * 16 + l15) * 32 + g * 8);
    #pragma unroll
    for (int nj = 0; nj < 4; ++nj)
      bfr[nj] = *(const bf16x8*)(Bs + (wn * 64 + nj * 16 + l15) * 32 + g * 8);
    #pragma unroll
    for (int mi = 0; mi < 4; ++mi)
      #pragma unroll
      for (int nj = 0; nj < 4; ++nj)
        acc[mi][nj] = __builtin_amdgcn_mfma_f32_16x16x32_bf16(af[mi], bfr[nj], acc[mi][nj], 0, 0, 0);
  }

  float bv4[4];
  #pragma unroll
  for (int nj = 0; nj < 4; ++nj) bv4[nj] = bias[n0 + wn * 64 + nj * 16 + l15];
  #pragma unroll
  for (int mi = 0; mi < 4; ++mi)
    #pragma unroll
    for (int nj = 0; nj < 4; ++nj)
      #pragma unroll
      for (int r = 0; r < 4; ++r) {
        const size_t row = m0 + wm * 64 + mi * 16 + g * 4 + r;
        const size_t col = n0 + wn * 64 + nj * 16 + l15;
        Y[row * 384 + col] = f2bf(acc[mi][nj][r] + bv4[nj]);
      }
}

// ---------------- final output projection (f32 out) ----------------
__global__ __launch_bounds__(256) void mfma_proj_out(const unsigned short* __restrict__ X,
                                                     const unsigned short* __restrict__ Wm,
                                                     const float* __restrict__ bias,
                                                     float* __restrict__ Y) {
  const int n0 = blockIdx.x * 128, m0 = blockIdx.y * 128;
  __shared__ __attribute__((aligned(16))) unsigned short As[128 * 32];
  __shared__ __attribute__((aligned(16))) unsigned short Bs[128 * 32];
  const int t = threadIdx.x;
  const int w = t >> 6, l = t & 63, l15 = l & 15, g = l >> 4;
  const int wm = w >> 1, wn = w & 1;

  f32x4 acc[4][4];
  #pragma unroll
  for (int i = 0; i < 4; ++i)
    #pragma unroll
    for (int j = 0; j < 4; ++j) acc[i][j] = {0.f, 0.f, 0.f, 0.f};

  for (int k0 = 0; k0 < 384; k0 += 32) {
    __syncthreads();
    #pragma unroll
    for (int a = 0; a < 2; ++a) {
      const int c = w * 2 + a;
      const int row = c * 16 + (l >> 2), kc = (l & 3) * 8;
      gload16(X  + (size_t)(m0 + row) * 384 + k0 + kc, As + c * 512);
      gload16(Wm + (size_t)(n0 + row) * 384 + k0 + kc, Bs + c * 512);
    }
    __syncthreads();
    bf16x8 af[4], bfr[4];
    #pragma unroll
    for (int mi = 0; mi < 4; ++mi)
      af[mi] = *(const bf16x8*)(As + (wm * 64 + mi * 16 + l15) * 32 + g * 8);
    #pragma unroll
    for (int nj = 0; nj < 4; ++nj)
      bfr[nj] = *(const bf16x8*)(Bs + (wn * 64 + nj * 16 + l15) * 32 + g * 8);
    #pragma unroll
    for (int mi = 0; mi < 4; ++mi)
      #pragma unroll
      for (int nj = 0; nj < 4; ++nj)
        acc[mi][nj] = __builtin_amdgcn_mfma_f32_16x16x32_bf16(af[mi], bfr[nj], acc[mi][nj], 0, 0, 0);
  }

  float bv4[4];
  #pragma unroll
  for (int nj = 0; nj < 4; ++nj) bv4[nj] = bias[n0 + wn * 64 + nj * 16 + l15];
  #pragma unroll
  for (int mi = 0; mi < 4; ++mi)
    #pragma unroll
    for (int nj = 0; nj < 4; ++nj)
      #pragma unroll
      for (int r = 0; r < 4; ++r) {
        const size_t row = m0 + wm * 64 + mi * 16 + g * 4 + r;
        const size_t col = n0 + wn * 64 + nj * 16 + l15;
        Y[row * 384 + col] = acc[mi][nj][r] + bv4[nj];
      }
}

// ---------------- MFMA flash attention, no-max softmax, MFMA denominator ----------------
// One block per (head, window). KV tiles of 64, double-buffered, 1 barrier/tile.
// K staged via per-lane-gather global_load_lds into [ch][64][8]; V reg-staged transposed.
__global__ __launch_bounds__(256) void attn_mfma(const unsigned short* __restrict__ Qg,
                                                 const unsigned short* __restrict__ Kc,
                                                 const unsigned short* __restrict__ Vc,
                                                 const float* __restrict__ pb,
                                                 unsigned short* __restrict__ AttO) {
  __shared__ int kvbase[768];
  __shared__ float tb2s[12];
  __shared__ __attribute__((aligned(16))) unsigned short Ks[2][3072];    // [buf][ch][tok][8]
  __shared__ __attribute__((aligned(16))) unsigned short Vt[2][64 * 68]; // [buf][d(0..47)+ones(48..63)][kv]
  __shared__ __attribute__((aligned(16))) unsigned short Ps[4][64 * 36]; // per-wave P^T swizzled

  const int t = threadIdx.x;
  const int head = blockIdx.x >> 7, win = blockIdx.x & 127;
  const int b = win >> 6, wrem = win & 63, wi = wrem >> 3, wj = wrem & 7;
  const int w = t >> 6, l = t & 63, l15 = l & 15, g = l >> 4;

  for (int j = t; j < 768; j += 256) {
    int o, within;
    if (j < 256)      { o = j >> 6;               within = j & 63; }
    else if (j < 512) { o = 4;                    within = j - 256; }
    else              { o = 5 + ((j - 512) >> 6); within = j & 63; }
    int base;
    if (o == 4) {
      int r = within >> 4, c = within & 15;
      base = ((b * 128 + wi * 16 + r) * 128 + wj * 16 + c) * 384;
    } else {
      int di = o / 3 - 1, dj = o - (o / 3) * 3 - 1;
      int t0 = within >> 3, t1 = within & 7;
      int p0 = 8 * (1 + di + wi) + t0, p1 = 8 * (1 + dj + wj) + t1;
      base = (NTOK + (b * 80 + p0) * 80 + p1) * 384;
    }
    kvbase[j] = base + head * 48;
  }
  if (t < 12) {
    int o = (t < 4) ? t : ((t < 8) ? 4 : t - 3);
    tb2s[t] = (o == 4) ? 0.0f : (-pb[head * 9 + o] * LOG2E);
  }
  // ones rows (d=48) + zero rows (49..63) in both Vt buffers, for MFMA denominator
  for (int idx = t; idx < 2 * 16 * 68; idx += 256) {
    const int bu = idx / 1088, rem = idx - bu * 1088;
    const int rr = rem / 68, cc = rem - rr * 68;
    Vt[bu][(48 + rr) * 68 + cc] = (rr == 0) ? 0x3F80 : 0;
  }

  const float SCALE2 = 0.14433756729740643f * LOG2E;  // 48^-0.5 * log2e
  const bf16x8 z8 = {0, 0, 0, 0, 0, 0, 0, 0};

  bf16x8 qf[4][2];
  #pragma unroll
  for (int nf = 0; nf < 4; ++nf) {
    const int tok = ((b * 128 + wi * 16 + w * 4 + nf) * 128 + wj * 16 + l15);
    const unsigned short* qp = Qg + (size_t)tok * 384 + head * 48;
    qf[nf][0] = *(const bf16x8*)(qp + g * 8);
    qf[nf][1] = (g < 2) ? *(const bf16x8*)(qp + 32 + g * 8) : z8;
  }

  f32x4 Oacc[4][4];
  #pragma unroll
  for (int mo = 0; mo < 4; ++mo)
    #pragma unroll
    for (int nf = 0; nf < 4; ++nf) Oacc[mo][nf] = {0.f, 0.f, 0.f, 0.f};

  __syncthreads();   // kvbase / tb2s / ones rows ready

  // prologue: issue tile 0 (K -> LDS-direct, V -> regs)
  {
    const int kvb = kvbase[l];
    gload16(Kc + kvb + w * 8, &Ks[0][w * 512]);
    if (w < 2) gload16(Kc + kvb + (4 + w) * 8, &Ks[0][(4 + w) * 512]);
  }
  uint4 va0, va1;
  {
    const int kvb = kvbase[l];
    va0 = *(const uint4*)(Vc + kvb + w * 8);
    va1 = (w < 2) ? *(const uint4*)(Vc + kvb + (4 + w) * 8) : make_uint4(0, 0, 0, 0);
  }

  for (int T = 0; T < 12; ++T) {
    const int buf = T & 1;
    asm volatile("s_waitcnt vmcnt(0)" ::: "memory");   // K_T in LDS (own wave), V_T in regs
    {
      const unsigned short* u0 = (const unsigned short*)&va0;
      #pragma unroll
      for (int s = 0; s < 8; ++s) Vt[buf][(w * 8 + s) * 68 + l] = u0[s];
      if (w < 2) {
        const unsigned short* u1 = (const unsigned short*)&va1;
        #pragma unroll
        for (int s = 0; s < 8; ++s) Vt[buf][((4 + w) * 8 + s) * 68 + l] = u1[s];
      }
    }
    __syncthreads();   // all waves: K_T drained, V_T written, compute T-1 done
    if (T < 11) {
      const int kvb2 = kvbase[(T + 1) * 64 + l];
      gload16(Kc + kvb2 + w * 8, &Ks[buf ^ 1][w * 512]);
      if (w < 2) gload16(Kc + kvb2 + (4 + w) * 8, &Ks[buf ^ 1][(4 + w) * 512]);
      va0 = *(const uint4*)(Vc + kvb2 + w * 8);
      if (w < 2) va1 = *(const uint4*)(Vc + kvb2 + (4 + w) * 8);
    }

    const float tb = tb2s[T];
    #pragma unroll
    for (int h = 0; h < 2; ++h) {
      bf16x8 ka[2][2];
      #pragma unroll
      for (int mi = 0; mi < 2; ++mi) {
        const int krow = h * 32 + mi * 16 + l15;
        ka[mi][0] = *(const bf16x8*)&Ks[buf][g * 512 + krow * 8];
        ka[mi][1] = (g < 2) ? *(const bf16x8*)&Ks[buf][(4 + g) * 512 + krow * 8] : z8;
      }
      #pragma unroll
      for (int nf = 0; nf < 4; ++nf) {
        f32x4 sf0 = {0.f, 0.f, 0.f, 0.f}, sf1 = {0.f, 0.f, 0.f, 0.f};
        sf0 = __builtin_amdgcn_mfma_f32_16x16x32_bf16(ka[0][0], qf[nf][0], sf0, 0, 0, 0);
        sf0 = __builtin_amdgcn_mfma_f32_16x16x32_bf16(ka[0][1], qf[nf][1], sf0, 0, 0, 0);
        sf1 = __builtin_amdgcn_mfma_f32_16x16x32_bf16(ka[1][0], qf[nf][0], sf1, 0, 0, 0);
        sf1 = __builtin_amdgcn_mfma_f32_16x16x32_bf16(ka[1][1], qf[nf][1], sf1, 0, 0, 0);
        float p[8];
        #pragma unroll
        for (int r = 0; r < 4; ++r) {
          p[r]     = fast_exp2(fmaf(sf0[r], SCALE2, tb));
          p[4 + r] = fast_exp2(fmaf(sf1[r], SCALE2, tb));
        }
        #pragma unroll
        for (int mi = 0; mi < 2; ++mi) {
          ushort4 pk = make_ushort4(f2bf(p[mi * 4 + 0]), f2bf(p[mi * 4 + 1]),
                                    f2bf(p[mi * 4 + 2]), f2bf(p[mi * 4 + 3]));
          const int chunk = mi * 2 + (g >> 1);
          *(ushort4*)&Ps[w][(nf * 16 + l15) * 36 + ((chunk ^ (l15 & 3)) << 3) + ((g & 1) << 2)] = pk;
        }
      }
      // PV (+ denominator row 48 via mo=3)
      bf16x8 pbf[4];
      #pragma unroll
      for (int nf = 0; nf < 4; ++nf) {
        const unsigned short* pp = &Ps[w][(nf * 16 + l15) * 36 + ((g ^ (l15 & 3)) << 3)];
        union { bf16x8 v; ushort4 u[2]; } cv;
        cv.u[0] = *(const ushort4*)pp;
        cv.u[1] = *(const ushort4*)(pp + 4);
        pbf[nf] = cv.v;
      }
      #pragma unroll
      for (int mo = 0; mo < 4; ++mo) {
        const unsigned short* vp = &Vt[buf][(mo * 16 + l15) * 68 + h * 32 + g * 8];
        union { bf16x8 v; ushort4 u[2]; } cv;
        cv.u[0] = *(const ushort4*)vp;
        cv.u[1] = *(const ushort4*)(vp + 4);
        bf16x8 va = cv.v;
        #pragma unroll
        for (int nf = 0; nf < 4; ++nf)
          Oacc[mo][nf] = __builtin_amdgcn_mfma_f32_16x16x32_bf16(va, pbf[nf], Oacc[mo][nf], 0, 0, 0);
      }
    }
  }

  #pragma unroll
  for (int nf = 0; nf < 4; ++nf) {
    const float denom = __shfl(Oacc[3][nf][0], l15, 64);   // row 48 = sum(p), held by lane (g=0,l15)
    const float inv = 1.0f / denom;
    const int tok = ((b * 128 + wi * 16 + w * 4 + nf) * 128 + wj * 16 + l15);
    unsigned short* op = AttO + (size_t)tok * 384 + head * 48;
    #pragma unroll
    for (int mo = 0; mo < 3; ++mo) {
      ushort4 u = make_ushort4(f2bf(Oacc[mo][nf][0] * inv), f2bf(Oacc[mo][nf][1] * inv),
                               f2bf(Oacc[mo][nf][2] * inv), f2bf(Oacc[mo][nf][3] * inv));
      *(ushort4*)(op + mo * 16 + g * 4) = u;
    }
  }
}

extern "C" void kernel_launch(void* const* d_in, const int* in_sizes, int n_in,
                              void* d_out, int out_size, void* d_ws, size_t ws_size,
                              hipStream_t stream) {
  const float* x  = (const float*)d_in[0];
  const float* Wq = (const float*)d_in[1];
  const float* bq = (const float*)d_in[2];
  const float* Wk = (const float*)d_in[3];
  const float* bk = (const float*)d_in[4];
  const float* Wv = (const float*)d_in[5];
  const float* bv = (const float*)d_in[6];
  const float* Wo = (const float*)d_in[7];
  const float* bo = (const float*)d_in[8];
  const float* pb = (const float*)d_in[9];

  // ws layout (bytes), total ~106 MB:
  //   Wt   : 4*384*384*2 = 1,179,648
  //   P    : 12800*384*2 = 9,830,400
  //   Kcat : 45568*384*2 = 34,996,224
  //   Vcat : 45568*384*2 = 34,996,224
  //   xb/AttO (aliased, sequential lifetimes): 32768*384*2 = 25,165,824
  // Qb lives in d_out's first half (dead before final proj writes d_out).
  char* ws = (char*)d_ws;
  unsigned short* Wt   = (unsigned short*)(ws);
  unsigned short* P    = (unsigned short*)(ws + 1179648ull);
  unsigned short* Kcat = (unsigned short*)(ws + 11010048ull);
  unsigned short* Vcat = (unsigned short*)(ws + 46006272ull);
  unsigned short* xb   = (unsigned short*)(ws + 81002496ull);
  unsigned short* AttO = xb;
  unsigned short* Qb   = (unsigned short*)d_out;

  convert_x<<<6144, 256, 0, stream>>>(x, xb);
  pool_kernel<<<12800, 128, 0, stream>>>(xb, P);
  transpose_w<<<dim3(12, 12, 4), 256, 0, stream>>>(Wq, Wk, Wv, Wo, Wt);
  mfma_proj_fused<<<dim3(15, 256), 256, 0, stream>>>(xb, P, Wt, bq, bk, bv, Qb, Kcat, Vcat);
  attn_mfma<<<1024, 256, 0, stream>>>(Qb, Kcat, Vcat, pb, AttO);
  mfma_proj_out<<<dim3(3, 256), 256, 0, stream>>>(AttO, Wt + 3 * 147456, bo, (float*)d_out);
}